// Round 7
// baseline (4183.078 us; speedup 1.0000x reference)
//
#include <hip/hip_runtime.h>
#include <stdint.h>

// ---------------------------------------------------------------------------
// LSTM-VAE persistent kernel, MI355X (gfx950).  B=128, T=512, I=L=64, H=512,
// 100 decoder steps.  fp32 in/out; bf16 MFMA internal.
//
// 128 WGs = 8 batch-groups(g) x 16 hidden-slices(s), block=512 (8 waves).
// Slice owns 32 hidden dims = 128 interleaved gate rows [i0,f0,g0,o0,...];
// W_hh slice in 64 VGPRs/lane as MFMA B-fragments. Decoder folds x_hat via
// W_comb = W_hh_dec + W_ih_dec@W_out; x_hat tiles spread over slices 0-3.
//
// Round-7 sync: SELF-SIGNALING DATA, no flags, no drains (all removed from
// the critical path). h is exchanged as u64 = 4 bf16 whose LSBs carry a
// 1-bit tag = (round>>1)&1. Double buffer hbuf[round&1]; stale data in a
// buffer is exactly 2 rounds old -> opposite tag; "ahead" writes impossible
// (publishing r+2 transitively requires all slices staged r). Consumers
// poll their own 4 u64 words (agent-scope relaxed atomics at the LLC -
// the only protocol verified safe on this chip: rounds 4-5) until tags
// match. hbuf1 is initialized to 0x01 bytes so virgin tag(1) != first-use
// tag(0). LSB steal costs <=1 ULP bf16 on h (absmax budget 4.6e-3).
// One flag round remains for the one-time z exchange.
// ---------------------------------------------------------------------------

typedef short short8 __attribute__((ext_vector_type(8)));
typedef float f32x4 __attribute__((ext_vector_type(4)));

#define WS_FLAGS  0           // 8 g x 16 s x 128 B
#define WS_HBUF0  16384       // 128 KB
#define WS_HBUF1  147456      // 128 KB (init 0x01)
#define WS_Z      278528      // 32 KB fp32
#define WS_BCOMB  311296      // 8 KB fp32
#define WS_WCOMB  319488      // 2 MB bf16
#define WS_SEQB   2416640     // 8 MB bf16 seq
#define WS_END    10805248

#define TAGM 0x0001000100010001ull

static __device__ __forceinline__ float b2f(unsigned short u) {
    return __builtin_bit_cast(float, (unsigned int)u << 16);
}
static __device__ __forceinline__ unsigned short f2b(float f) {
    unsigned int u = __builtin_bit_cast(unsigned int, f);
    unsigned int r = u + 0x7FFFu + ((u >> 16) & 1u);  // RNE
    return (unsigned short)(r >> 16);
}
static __device__ __forceinline__ float sigm(float x)  { return 1.0f / (1.0f + __expf(-x)); }
static __device__ __forceinline__ float tanhx(float x) { return 1.0f - 2.0f / (__expf(2.0f * x) + 1.0f); }

static __device__ __forceinline__ short8 cvt8(const float* p) {
    const float4 a = ((const float4*)p)[0];
    const float4 b = ((const float4*)p)[1];
    short8 r;
    r[0] = (short)f2b(a.x); r[1] = (short)f2b(a.y);
    r[2] = (short)f2b(a.z); r[3] = (short)f2b(a.w);
    r[4] = (short)f2b(b.x); r[5] = (short)f2b(b.y);
    r[6] = (short)f2b(b.z); r[7] = (short)f2b(b.w);
    return r;
}

// ---------------------------------------------------------------------------
// Prologue A: seq fp32 -> bf16
// ---------------------------------------------------------------------------
__global__ void __launch_bounds__(256)
seqcvt_kernel(const float* __restrict__ src, unsigned short* __restrict__ dst)
{
    int i = (blockIdx.x * 256 + threadIdx.x) * 4;
    float4 v = *(const float4*)(src + i);
    uint32_t lo = (uint32_t)f2b(v.x) | ((uint32_t)f2b(v.y) << 16);
    uint32_t hi = (uint32_t)f2b(v.z) | ((uint32_t)f2b(v.w) << 16);
    uint2 o; o.x = lo; o.y = hi;
    *(uint2*)(dst + i) = o;
}

// ---------------------------------------------------------------------------
// Prologue B: W_comb = W_hh_dec + W_ih_dec @ W_out (bf16 out), b_comb (fp32)
// ---------------------------------------------------------------------------
__global__ void __launch_bounds__(256)
wcomb_kernel(const float* __restrict__ Wih_d,
             const float* __restrict__ Whh_d,
             const float* __restrict__ Wout,
             const float* __restrict__ bih_d,
             const float* __restrict__ bhh_d,
             const float* __restrict__ bout,
             unsigned char* __restrict__ ws)
{
    __shared__ float Ash[64][64];
    __shared__ float Bsh[64][65];
    const int bid = blockIdx.x, t = threadIdx.x;
    const int gt0 = (bid >> 3) * 64, ht0 = (bid & 7) * 64;
    for (int j = 0; j < 16; ++j) {
        int idx = t + j * 256;
        int r = idx >> 6, c = idx & 63;
        Ash[r][c] = Wih_d[(size_t)(gt0 + r) * 64 + c];
        Bsh[r][c] = Wout[(size_t)r * 512 + ht0 + c];
    }
    __syncthreads();
    const int gl = t >> 2, hl0 = (t & 3) * 16;
    for (int hh = 0; hh < 16; ++hh) {
        float acc = 0.f;
        #pragma unroll
        for (int i = 0; i < 64; ++i) acc += Ash[gl][i] * Bsh[i][hl0 + hh];
        int g = gt0 + gl, h = ht0 + hl0 + hh;
        float v = Whh_d[(size_t)g * 512 + h] + acc;
        ((unsigned short*)(ws + WS_WCOMB))[(size_t)g * 512 + h] = f2b(v);
    }
    if ((bid & 7) == 0 && t < 64) {
        int g = gt0 + t;
        float acc = bih_d[g] + bhh_d[g];
        #pragma unroll
        for (int i = 0; i < 64; ++i) acc += bout[i] * Ash[t][i];
        ((float*)(ws + WS_BCOMB))[g] = acc;
    }
}

// ---------------------------------------------------------------------------
// Main persistent kernel
// ---------------------------------------------------------------------------
__global__ void __launch_bounds__(512, 2)
vae_persistent(const float* __restrict__ seq,
               const unsigned short* __restrict__ seqb,
               const float* __restrict__ eps,
               const float* __restrict__ Wih_e,
               const float* __restrict__ Whh_e,
               const float* __restrict__ bih_e,
               const float* __restrict__ bhh_e,
               const float* __restrict__ Wmean,
               const float* __restrict__ bmean,
               const float* __restrict__ Wlv,
               const float* __restrict__ blv,
               const float* __restrict__ Winit,
               const float* __restrict__ binit,
               const float* __restrict__ Whh_d,
               const float* __restrict__ bih_d,
               const float* __restrict__ bhh_d,
               const float* __restrict__ Wout,
               const float* __restrict__ bout,
               unsigned char* __restrict__ ws,
               float* __restrict__ out)
{
    __shared__ __align__(16) short Al[16 * 520];  // staged h tile (bf16)
    __shared__ float fbuf[128];                   // mean/logvar scratch
    __shared__ float zl[16 * 64];                 // z tile (fp32)

    const int tid  = threadIdx.x;
    const int g    = blockIdx.x & 7;        // batch group
    const int s    = blockIdx.x >> 3;       // hidden slice
    const int b0   = g * 16;
    const int lane = tid & 63;
    const int wv   = tid >> 6;
    const int col  = lane & 15;
    const int q    = lane >> 4;
    const int nloc = wv * 16 + col;
    const int gt   = nloc & 3;              // 0=i,1=f,2=g,3=o
    const int grow = gt * 512 + s * 32 + (nloc >> 2);

    uint32_t* flags = (uint32_t*)(ws + WS_FLAGS) + (size_t)g * 512;  // slice i @ [i*32]
    unsigned long long* hbuf0 = (unsigned long long*)(ws + WS_HBUF0);
    unsigned long long* hbuf1 = (unsigned long long*)(ws + WS_HBUF1);
    uint32_t* zbuf = (uint32_t*)(ws + WS_Z);

    float cst[4] = {0.f, 0.f, 0.f, 0.f};

    // ---- stage h (round R, self-signaling tags) into Al ------------------
    auto stage_h = [&](uint32_t R) {
        const unsigned long long* src = (R & 1) ? hbuf1 : hbuf0;
        const unsigned long long want = ((R >> 1) & 1) ? TAGM : 0ull;
        const int c2 = tid & 127, brow = tid >> 7;
        const unsigned long long* p[4];
        unsigned long long v[4];
        #pragma unroll
        for (int j = 0; j < 4; ++j) {
            p[j] = src + (size_t)(b0 + brow + 4 * j) * 128 + c2;
            v[j] = __hip_atomic_load(p[j], __ATOMIC_RELAXED, __HIP_MEMORY_SCOPE_AGENT);
        }
        for (;;) {
            unsigned long long m0 = (v[0] ^ want) & TAGM;
            unsigned long long m1 = (v[1] ^ want) & TAGM;
            unsigned long long m2 = (v[2] ^ want) & TAGM;
            unsigned long long m3 = (v[3] ^ want) & TAGM;
            if ((m0 | m1 | m2 | m3) == 0ull) break;
            if (m0) v[0] = __hip_atomic_load(p[0], __ATOMIC_RELAXED, __HIP_MEMORY_SCOPE_AGENT);
            if (m1) v[1] = __hip_atomic_load(p[1], __ATOMIC_RELAXED, __HIP_MEMORY_SCOPE_AGENT);
            if (m2) v[2] = __hip_atomic_load(p[2], __ATOMIC_RELAXED, __HIP_MEMORY_SCOPE_AGENT);
            if (m3) v[3] = __hip_atomic_load(p[3], __ATOMIC_RELAXED, __HIP_MEMORY_SCOPE_AGENT);
        }
        __syncthreads();                    // Al free (previous readers done)
        unsigned long long* dst = (unsigned long long*)Al;
        #pragma unroll
        for (int j = 0; j < 4; ++j)
            dst[(brow + 4 * j) * 130 + c2] = v[j];
        __syncthreads();
    };

    // ---- cell update + register-direct tagged publish --------------------
    auto cell_publish = [&](f32x4 acc, uint32_t R) {
        float act[4];
        #pragma unroll
        for (int r = 0; r < 4; ++r)
            act[r] = (gt == 2) ? tanhx(acc[r]) : sigm(acc[r]);
        int base = lane & ~3;
        #pragma unroll
        for (int r = 0; r < 4; ++r) {
            float vi = __shfl(act[r], base + 0);
            float vf = __shfl(act[r], base + 1);
            float vg = __shfl(act[r], base + 2);
            float vo = __shfl(act[r], base + 3);
            cst[r] = vf * cst[r] + vi * vg;
            act[r] = vo * tanhx(cst[r]);         // h for (row q*4+r, dim nloc>>2)
        }
        // pack h[row][wv*4 .. wv*4+3] into one u64 per row; 16 lanes store
        int rr = col & 3;
        float x = act[rr];                       // this lane's row-(q*4+rr) h
        float v0 = __shfl(x, q * 16 + 0 + rr);
        float v1 = __shfl(x, q * 16 + 4 + rr);
        float v2 = __shfl(x, q * 16 + 8 + rr);
        float v3 = __shfl(x, q * 16 + 12 + rr);
        if (col < 4) {
            unsigned long long u =
                  (unsigned long long)(f2b(v0) & 0xFFFEu)
                | ((unsigned long long)(f2b(v1) & 0xFFFEu) << 16)
                | ((unsigned long long)(f2b(v2) & 0xFFFEu) << 32)
                | ((unsigned long long)(f2b(v3) & 0xFFFEu) << 48);
            if ((R >> 1) & 1) u |= TAGM;
            unsigned long long* dst = (R & 1) ? hbuf1 : hbuf0;
            int row = q * 4 + col;
            __hip_atomic_store(dst + (size_t)(b0 + row) * 128 + s * 8 + wv, u,
                               __ATOMIC_RELAXED, __HIP_MEMORY_SCOPE_AGENT);
        }
    };

    short8 wfrag[16];
    auto load_wfrag_f32 = [&](const float* Wsrc) {
        #pragma unroll
        for (int kt = 0; kt < 16; ++kt)
            wfrag[kt] = cvt8(Wsrc + (size_t)grow * 512 + kt * 32 + q * 8);
    };
    auto load_wfrag_bf16 = [&](const unsigned short* Wsrc) {
        #pragma unroll
        for (int kt = 0; kt < 16; ++kt)
            wfrag[kt] = *(const short8*)((const short*)Wsrc +
                         (size_t)grow * 512 + kt * 32 + q * 8);
    };

    // ---------------- encoder: 512 steps ----------------
    load_wfrag_f32(Whh_e);
    short8 xwf[2];
    #pragma unroll
    for (int kt = 0; kt < 2; ++kt)
        xwf[kt] = cvt8(Wih_e + (size_t)grow * 64 + kt * 32 + q * 8);
    const float bias_e = bih_e[grow] + bhh_e[grow];

    auto load_x = [&](int t, short8* xf) {
        if (seqb) {
            const short* xs = (const short*)seqb + ((size_t)(b0 + col) * 512 + t) * 64 + q * 8;
            xf[0] = *(const short8*)(xs);
            xf[1] = *(const short8*)(xs + 32);
        } else {
            const float* xs = seq + ((size_t)(b0 + col) * 512 + t) * 64 + q * 8;
            xf[0] = cvt8(xs);
            xf[1] = cvt8(xs + 32);
        }
    };

    short8 xf[2];
    load_x(0, xf);
    for (uint32_t t = 0; t < 512; ++t) {
        stage_h(t);                          // t=0: hbuf0 zeros, tag 0 -> instant
        f32x4 acc = {bias_e, bias_e, bias_e, bias_e};
        acc = __builtin_amdgcn_mfma_f32_16x16x32_bf16(xf[0], xwf[0], acc, 0, 0, 0);
        acc = __builtin_amdgcn_mfma_f32_16x16x32_bf16(xf[1], xwf[1], acc, 0, 0, 0);
        if (t < 511) load_x(t + 1, xf);
        #pragma unroll
        for (int kt = 0; kt < 16; ++kt) {
            short8 a = *(const short8*)(Al + col * 520 + kt * 32 + q * 8);
            acc = __builtin_amdgcn_mfma_f32_16x16x32_bf16(a, wfrag[kt], acc, 0, 0, 0);
        }
        cell_publish(acc, t + 1);            // h_{t+1} at round t+1
    }

    // ---------------- VAE reparameterization (one-time flag round) --------
    stage_h(512);                            // Al = h_n
    if (tid < 128) {
        int which = tid >> 6, idx = tid & 63;
        int b = idx >> 2, ldl = idx & 3;
        int ld = s * 4 + ldl;
        const float* wrow = (which ? Wlv : Wmean) + (size_t)ld * 512;
        float a = (which ? blv[ld] : bmean[ld]);
        for (int k = 0; k < 512; ++k)
            a += b2f((unsigned short)Al[b * 520 + k]) * wrow[k];
        out[819200 + which * 8192 + (size_t)(b0 + b) * 64 + ld] = a;
        fbuf[which * 64 + idx] = a;
    }
    __syncthreads();
    if (wv == 0) {
        int b = lane >> 2, ldl = lane & 3;
        int ld = s * 4 + ldl;
        float m = fbuf[lane], lv = fbuf[64 + lane];
        float e = eps[(size_t)(b0 + b) * 64 + ld];
        float z = m + e * __expf(0.5f * lv);
        __hip_atomic_store(zbuf + (size_t)(b0 + b) * 64 + ld,
                           __builtin_bit_cast(uint32_t, z),
                           __ATOMIC_RELAXED, __HIP_MEMORY_SCOPE_AGENT);
        asm volatile("s_waitcnt vmcnt(0)" ::: "memory");
        if (lane == 0)
            __hip_atomic_store(&flags[s * 32], 1u,
                               __ATOMIC_RELAXED, __HIP_MEMORY_SCOPE_AGENT);
    }
    if (wv == 0 && lane < 16)
        while (__hip_atomic_load(&flags[lane * 32], __ATOMIC_RELAXED,
                                 __HIP_MEMORY_SCOPE_AGENT) < 1u) {}
    __syncthreads();

    // h_dec0 = z @ W_init^T + b_init, computed locally into Al
    #pragma unroll
    for (int j = 0; j < 2; ++j) {
        int idx = tid + j * 512;
        int b = idx >> 6, l = idx & 63;
        uint32_t v = __hip_atomic_load(zbuf + (size_t)(b0 + b) * 64 + l,
                                       __ATOMIC_RELAXED, __HIP_MEMORY_SCOPE_AGENT);
        zl[b * 64 + l] = __builtin_bit_cast(float, v);
    }
    __syncthreads();
    {
        int b = tid >> 5, c = tid & 31;
        #pragma unroll
        for (int j = 0; j < 16; ++j) {
            int hd = c * 16 + j;
            float a = binit[hd];
            const float* wr = Winit + (size_t)hd * 64;
            #pragma unroll
            for (int l = 0; l < 64; ++l) a += zl[b * 64 + l] * wr[l];
            Al[b * 520 + hd] = (short)f2b(a);
        }
    }
    #pragma unroll
    for (int r = 0; r < 4; ++r) cst[r] = 0.f;
    __syncthreads();

    // ---------------- decoder: 100 steps; h_{d+1} published at R=513+d ----
    short8 wof[16];
    float xbias = 0.f;
    if (s < 4 && wv == 0) {                  // x_hat tile s (cols s*16..+15)
        xbias = bout[s * 16 + col];
        #pragma unroll
        for (int kt = 0; kt < 16; ++kt)
            wof[kt] = cvt8(Wout + (size_t)(s * 16 + col) * 512 + kt * 32 + q * 8);
    }
    auto xhat_emit = [&](int d) {            // x_hat_d from Al (= h_{d+1})
        f32x4 a2 = {xbias, xbias, xbias, xbias};
        #pragma unroll
        for (int kt = 0; kt < 16; ++kt) {
            short8 a = *(const short8*)(Al + col * 520 + kt * 32 + q * 8);
            a2 = __builtin_amdgcn_mfma_f32_16x16x32_bf16(a, wof[kt], a2, 0, 0, 0);
        }
        #pragma unroll
        for (int r = 0; r < 4; ++r) {
            int b = q * 4 + r;
            out[((size_t)(b0 + b) * 100 + d) * 64 + s * 16 + col] = a2[r];
        }
    };

    load_wfrag_f32(Whh_d);                   // step 0: x0 == 0
    float bias = bih_d[grow] + bhh_d[grow];
    for (uint32_t d = 0; d < 100; ++d) {
        if (d > 0) stage_h(512 + d);         // Al = h_d (pub at step d-1)
        f32x4 acc = {bias, bias, bias, bias};
        #pragma unroll
        for (int kt = 0; kt < 16; ++kt) {
            short8 a = *(const short8*)(Al + col * 520 + kt * 32 + q * 8);
            acc = __builtin_amdgcn_mfma_f32_16x16x32_bf16(a, wfrag[kt], acc, 0, 0, 0);
        }
        cell_publish(acc, 513 + d);
        if (d >= 1 && s < 4 && wv == 0) xhat_emit(d - 1);   // off critical path
        if (d == 0) {
            load_wfrag_bf16((const unsigned short*)(ws + WS_WCOMB));
            bias = ((const float*)(ws + WS_BCOMB))[grow];
        }
    }
    stage_h(612);                            // h_100
    if (s < 4 && wv == 0) xhat_emit(99);
}

extern "C" void kernel_launch(void* const* d_in, const int* in_sizes, int n_in,
                              void* d_out, int out_size, void* d_ws, size_t ws_size,
                              hipStream_t stream) {
    (void)in_sizes; (void)n_in; (void)out_size;
    const float* seq   = (const float*)d_in[0];
    const float* eps   = (const float*)d_in[2];
    const float* Wih_e = (const float*)d_in[3];
    const float* Whh_e = (const float*)d_in[4];
    const float* bih_e = (const float*)d_in[5];
    const float* bhh_e = (const float*)d_in[6];
    const float* Wmean = (const float*)d_in[7];
    const float* bmean = (const float*)d_in[8];
    const float* Wlv   = (const float*)d_in[9];
    const float* blv   = (const float*)d_in[10];
    const float* Winit = (const float*)d_in[11];
    const float* binit = (const float*)d_in[12];
    const float* Wih_d = (const float*)d_in[13];
    const float* Whh_d = (const float*)d_in[14];
    const float* bih_d = (const float*)d_in[15];
    const float* bhh_d = (const float*)d_in[16];
    const float* Wout  = (const float*)d_in[17];
    const float* bout  = (const float*)d_in[18];
    unsigned char* ws = (unsigned char*)d_ws;
    float* out = (float*)d_out;

    const bool have_seqb = ws_size >= (size_t)WS_END;
    unsigned short* seqb = have_seqb ? (unsigned short*)(ws + WS_SEQB) : nullptr;

    // flags + hbuf0 -> 0x00 (h0 = 0, tag 0); hbuf1 -> 0x01 (virgin tag 1)
    hipMemsetAsync(ws, 0, WS_HBUF1, stream);
    hipMemsetAsync(ws + WS_HBUF1, 0x01, WS_Z - WS_HBUF1, stream);
    if (have_seqb)
        seqcvt_kernel<<<4096, 256, 0, stream>>>(seq, seqb);
    wcomb_kernel<<<256, 256, 0, stream>>>(Wih_d, Whh_d, Wout, bih_d, bhh_d, bout, ws);
    vae_persistent<<<128, 512, 0, stream>>>(
        seq, seqb, eps, Wih_e, Whh_e, bih_e, bhh_e,
        Wmean, bmean, Wlv, blv, Winit, binit,
        Whh_d, bih_d, bhh_d, Wout, bout, ws, out);
}

// Round 8
// 1880.193 us; speedup vs baseline: 2.2248x; 2.2248x over previous
//
#include <hip/hip_runtime.h>
#include <stdint.h>

// ---------------------------------------------------------------------------
// LSTM-VAE persistent kernel, MI355X (gfx950).  B=128, T=512, I=L=64, H=512,
// 100 decoder steps.  fp32 in/out; bf16 MFMA internal.
//
// 128 WGs = 8 batch-groups(g) x 16 hidden-slices(s), block=512 (8 waves).
// Slice owns 32 hidden dims = 128 interleaved gate rows [i0,f0,g0,o0,...];
// W_hh slice in 64 VGPRs/lane as MFMA B-fragments. Decoder folds x_hat via
// W_comb = W_hh_dec + W_ih_dec@W_out; x_hat tiles on wave 7 of slices 0-3.
//
// Round-8 sync: round-5 flag protocol (passed @2393us) with a COALESCED
// coherent data path. Rationale (r7 post-mortem): per-lane agent-scope
// atomics are uncoalescable single-beat transactions at the memory side;
// 32K of them per group-step was the real cost. Normal vector ops with
// explicit `sc0 sc1` have the same coherence point (bypass L1+L2, serviced
// at the device-coherent LLC) but coalesce into full-line bursts.
//   publish: wave 0 stores 16x dwordx4 sc0sc1, s_waitcnt vmcnt(0),
//            lane0 sets flag (agent atomic).
//   wait:    wave 0 lanes 0-15 poll the 16 per-slice flag lines.
//   stage:   all threads load 2x dwordx4 sc0sc1 (wave-coalesced), -> LDS.
// No cache-maintenance fences anywhere (round 3: 14us/step). No sc0-only
// L2 protocol (round 6: unsound, hangs). Round r in hbuf[r&1]; publishing
// r requires all flags >= r-1, which transitively certifies all slices
// staged r-2 -> overwrite of hbuf[r&1] is safe.
// ---------------------------------------------------------------------------

typedef short short8 __attribute__((ext_vector_type(8)));
typedef float f32x4 __attribute__((ext_vector_type(4)));
typedef unsigned int u32x4 __attribute__((ext_vector_type(4)));

#define WS_FLAGS  0           // 8 g x 16 s x 128 B
#define WS_HBUF0  16384       // 128 KB
#define WS_HBUF1  147456      // 128 KB
#define WS_Z      278528      // 32 KB fp32
#define WS_BCOMB  311296      // 8 KB fp32
#define WS_WCOMB  319488      // 2 MB bf16
#define WS_SEQB   2416640     // 8 MB bf16 seq
#define WS_END    10805248
#define WS_ZERO   WS_HBUF1    // memset flags + hbuf0 (h0 = 0)

static __device__ __forceinline__ float b2f(unsigned short u) {
    return __builtin_bit_cast(float, (unsigned int)u << 16);
}
static __device__ __forceinline__ unsigned short f2b(float f) {
    unsigned int u = __builtin_bit_cast(unsigned int, f);
    unsigned int r = u + 0x7FFFu + ((u >> 16) & 1u);  // RNE
    return (unsigned short)(r >> 16);
}
static __device__ __forceinline__ float sigm(float x)  { return 1.0f / (1.0f + __expf(-x)); }
static __device__ __forceinline__ float tanhx(float x) { return 1.0f - 2.0f / (__expf(2.0f * x) + 1.0f); }

static __device__ __forceinline__ short8 cvt8(const float* p) {
    const float4 a = ((const float4*)p)[0];
    const float4 b = ((const float4*)p)[1];
    short8 r;
    r[0] = (short)f2b(a.x); r[1] = (short)f2b(a.y);
    r[2] = (short)f2b(a.z); r[3] = (short)f2b(a.w);
    r[4] = (short)f2b(b.x); r[5] = (short)f2b(b.y);
    r[6] = (short)f2b(b.z); r[7] = (short)f2b(b.w);
    return r;
}

// --- coherent (LLC-served, L1/L2-bypass) coalesced ops: sc0 sc1 ----------
static __device__ __forceinline__ void load2x16_cc(const void* p0, const void* p1,
                                                   u32x4& v0, u32x4& v1) {
    asm volatile("global_load_dwordx4 %0, %2, off sc0 sc1\n\t"
                 "global_load_dwordx4 %1, %3, off sc0 sc1\n\t"
                 "s_waitcnt vmcnt(0)"
                 : "=&v"(v0), "=&v"(v1) : "v"(p0), "v"(p1) : "memory");
}
static __device__ __forceinline__ void store16_cc(void* p, u32x4 v) {
    asm volatile("global_store_dwordx4 %0, %1, off sc0 sc1"
                 :: "v"(p), "v"(v) : "memory");
}
static __device__ __forceinline__ void drain_vm() {
    asm volatile("s_waitcnt vmcnt(0)" ::: "memory");
}

// ---------------------------------------------------------------------------
// Prologue A: seq fp32 -> bf16
// ---------------------------------------------------------------------------
__global__ void __launch_bounds__(256)
seqcvt_kernel(const float* __restrict__ src, unsigned short* __restrict__ dst)
{
    int i = (blockIdx.x * 256 + threadIdx.x) * 4;
    float4 v = *(const float4*)(src + i);
    uint32_t lo = (uint32_t)f2b(v.x) | ((uint32_t)f2b(v.y) << 16);
    uint32_t hi = (uint32_t)f2b(v.z) | ((uint32_t)f2b(v.w) << 16);
    uint2 o; o.x = lo; o.y = hi;
    *(uint2*)(dst + i) = o;
}

// ---------------------------------------------------------------------------
// Prologue B: W_comb = W_hh_dec + W_ih_dec @ W_out (bf16 out), b_comb (fp32)
// ---------------------------------------------------------------------------
__global__ void __launch_bounds__(256)
wcomb_kernel(const float* __restrict__ Wih_d,
             const float* __restrict__ Whh_d,
             const float* __restrict__ Wout,
             const float* __restrict__ bih_d,
             const float* __restrict__ bhh_d,
             const float* __restrict__ bout,
             unsigned char* __restrict__ ws)
{
    __shared__ float Ash[64][64];
    __shared__ float Bsh[64][65];
    const int bid = blockIdx.x, t = threadIdx.x;
    const int gt0 = (bid >> 3) * 64, ht0 = (bid & 7) * 64;
    for (int j = 0; j < 16; ++j) {
        int idx = t + j * 256;
        int r = idx >> 6, c = idx & 63;
        Ash[r][c] = Wih_d[(size_t)(gt0 + r) * 64 + c];
        Bsh[r][c] = Wout[(size_t)r * 512 + ht0 + c];
    }
    __syncthreads();
    const int gl = t >> 2, hl0 = (t & 3) * 16;
    for (int hh = 0; hh < 16; ++hh) {
        float acc = 0.f;
        #pragma unroll
        for (int i = 0; i < 64; ++i) acc += Ash[gl][i] * Bsh[i][hl0 + hh];
        int g = gt0 + gl, h = ht0 + hl0 + hh;
        float v = Whh_d[(size_t)g * 512 + h] + acc;
        ((unsigned short*)(ws + WS_WCOMB))[(size_t)g * 512 + h] = f2b(v);
    }
    if ((bid & 7) == 0 && t < 64) {
        int g = gt0 + t;
        float acc = bih_d[g] + bhh_d[g];
        #pragma unroll
        for (int i = 0; i < 64; ++i) acc += bout[i] * Ash[t][i];
        ((float*)(ws + WS_BCOMB))[g] = acc;
    }
}

// ---------------------------------------------------------------------------
// Main persistent kernel
// ---------------------------------------------------------------------------
__global__ void __launch_bounds__(512, 2)
vae_persistent(const float* __restrict__ seq,
               const unsigned short* __restrict__ seqb,
               const float* __restrict__ eps,
               const float* __restrict__ Wih_e,
               const float* __restrict__ Whh_e,
               const float* __restrict__ bih_e,
               const float* __restrict__ bhh_e,
               const float* __restrict__ Wmean,
               const float* __restrict__ bmean,
               const float* __restrict__ Wlv,
               const float* __restrict__ blv,
               const float* __restrict__ Winit,
               const float* __restrict__ binit,
               const float* __restrict__ Whh_d,
               const float* __restrict__ bih_d,
               const float* __restrict__ bhh_d,
               const float* __restrict__ Wout,
               const float* __restrict__ bout,
               unsigned char* __restrict__ ws,
               float* __restrict__ out)
{
    __shared__ __align__(16) short Al[16 * 520];  // staged h tile (bf16)
    __shared__ __align__(16) short Ho[512];       // h write-back staging [16][32]
    __shared__ float fbuf[128];                   // mean/logvar scratch
    __shared__ float zl[16 * 64];                 // z tile (fp32)

    const int tid  = threadIdx.x;
    const int g    = blockIdx.x & 7;        // batch group
    const int s    = blockIdx.x >> 3;       // hidden slice
    const int b0   = g * 16;
    const int lane = tid & 63;
    const int wv   = tid >> 6;
    const int col  = lane & 15;
    const int q    = lane >> 4;
    const int nloc = wv * 16 + col;
    const int gt   = nloc & 3;              // 0=i,1=f,2=g,3=o
    const int grow = gt * 512 + s * 32 + (nloc >> 2);

    uint32_t* flags = (uint32_t*)(ws + WS_FLAGS) + (size_t)g * 512;  // slice i @ [i*32]
    unsigned char* hbuf0 = ws + WS_HBUF0;
    unsigned char* hbuf1 = ws + WS_HBUF1;
    uint32_t* zbuf = (uint32_t*)(ws + WS_Z);

    float cst[4] = {0.f, 0.f, 0.f, 0.f};

    // ---- wait for round R (wave 0 polls 16 flag lines) + stage into Al ---
    auto wait_and_stage = [&](uint32_t R) {
        if (wv == 0 && lane < 16) {
            while (__hip_atomic_load(&flags[lane * 32], __ATOMIC_RELAXED,
                                     __HIP_MEMORY_SCOPE_AGENT) < R) {}
        }
        __syncthreads();                       // release all waves to load
        const unsigned char* src = (R & 1) ? hbuf1 : hbuf0;
        const int b = tid >> 5, c = tid & 31;  // 16 rows x 32 chunks of 32 B
        const unsigned char* p0 = src + (size_t)(b0 + b) * 1024 + c * 32;
        u32x4 v0, v1;
        load2x16_cc(p0, p0 + 16, v0, v1);
        u32x4* dst = (u32x4*)Al;               // row stride 65 u32x4 = 520 shorts
        dst[b * 65 + c * 2 + 0] = v0;
        dst[b * 65 + c * 2 + 1] = v1;
        __syncthreads();
    };

    // ---- publish round R (wave 0: coalesced stores, drain, flag) ---------
    auto publish_h = [&](uint32_t R) {
        if (wv == 0) {
            unsigned char* dst = (R & 1) ? hbuf1 : hbuf0;
            int row = lane >> 2, part = lane & 3;          // 16 B per lane
            u32x4 v = ((const u32x4*)Ho)[lane];
            store16_cc(dst + (size_t)(b0 + row) * 1024 + s * 64 + part * 16, v);
            drain_vm();
            if (lane == 0)
                __hip_atomic_store(&flags[s * 32], R, __ATOMIC_RELAXED,
                                   __HIP_MEMORY_SCOPE_AGENT);
        }
    };

    short8 wfrag[16];
    auto load_wfrag_f32 = [&](const float* Wsrc) {
        #pragma unroll
        for (int kt = 0; kt < 16; ++kt)
            wfrag[kt] = cvt8(Wsrc + (size_t)grow * 512 + kt * 32 + q * 8);
    };
    auto load_wfrag_bf16 = [&](const unsigned short* Wsrc) {
        #pragma unroll
        for (int kt = 0; kt < 16; ++kt)
            wfrag[kt] = *(const short8*)((const short*)Wsrc +
                         (size_t)grow * 512 + kt * 32 + q * 8);
    };

    // activations + cell update; h slice left in Ho (sync before publish)
    auto cell_update = [&](f32x4 acc) {
        float act[4];
        #pragma unroll
        for (int r = 0; r < 4; ++r)
            act[r] = (gt == 2) ? tanhx(acc[r]) : sigm(acc[r]);
        int base = lane & ~3;
        #pragma unroll
        for (int r = 0; r < 4; ++r) {
            float vi = __shfl(act[r], base + 0);
            float vf = __shfl(act[r], base + 1);
            float vg = __shfl(act[r], base + 2);
            float vo = __shfl(act[r], base + 3);
            cst[r] = vf * cst[r] + vi * vg;
            act[r] = vo * tanhx(cst[r]);
        }
        if (gt == 0) {
            int hd4 = wv * 4 + (col >> 2);     // 0..31
            #pragma unroll
            for (int r = 0; r < 4; ++r)
                Ho[(q * 4 + r) * 32 + hd4] = (short)f2b(act[r]);
        }
    };

    // ---------------- encoder: 512 steps ----------------
    load_wfrag_f32(Whh_e);
    short8 xwf[2];
    #pragma unroll
    for (int kt = 0; kt < 2; ++kt)
        xwf[kt] = cvt8(Wih_e + (size_t)grow * 64 + kt * 32 + q * 8);
    const float bias_e = bih_e[grow] + bhh_e[grow];

    auto load_x = [&](int t, short8* xf) {
        if (seqb) {
            const short* xs = (const short*)seqb + ((size_t)(b0 + col) * 512 + t) * 64 + q * 8;
            xf[0] = *(const short8*)(xs);
            xf[1] = *(const short8*)(xs + 32);
        } else {
            const float* xs = seq + ((size_t)(b0 + col) * 512 + t) * 64 + q * 8;
            xf[0] = cvt8(xs);
            xf[1] = cvt8(xs + 32);
        }
    };

    short8 xf[2];
    load_x(0, xf);
    for (uint32_t t = 0; t < 512; ++t) {
        wait_and_stage(t);                   // t=0: flags 0 -> instant; hbuf0 = 0
        f32x4 acc = {bias_e, bias_e, bias_e, bias_e};
        acc = __builtin_amdgcn_mfma_f32_16x16x32_bf16(xf[0], xwf[0], acc, 0, 0, 0);
        acc = __builtin_amdgcn_mfma_f32_16x16x32_bf16(xf[1], xwf[1], acc, 0, 0, 0);
        if (t < 511) load_x(t + 1, xf);
        #pragma unroll
        for (int kt = 0; kt < 16; ++kt) {
            short8 a = *(const short8*)(Al + col * 520 + kt * 32 + q * 8);
            acc = __builtin_amdgcn_mfma_f32_16x16x32_bf16(a, wfrag[kt], acc, 0, 0, 0);
        }
        cell_update(acc);
        __syncthreads();
        publish_h(t + 1);                    // h_{t+1} -> round t+1
    }

    // ---------------- VAE reparameterization (flag 513 = z ready) ---------
    wait_and_stage(512);                     // Al = h_n
    if (tid < 128) {
        int which = tid >> 6, idx = tid & 63;
        int b = idx >> 2, ldl = idx & 3;
        int ld = s * 4 + ldl;
        const float* wrow = (which ? Wlv : Wmean) + (size_t)ld * 512;
        float a = (which ? blv[ld] : bmean[ld]);
        for (int k = 0; k < 512; ++k)
            a += b2f((unsigned short)Al[b * 520 + k]) * wrow[k];
        out[819200 + which * 8192 + (size_t)(b0 + b) * 64 + ld] = a;
        fbuf[which * 64 + idx] = a;
    }
    __syncthreads();
    if (wv == 0) {
        int b = lane >> 2, ldl = lane & 3;
        int ld = s * 4 + ldl;
        float m = fbuf[lane], lv = fbuf[64 + lane];
        float e = eps[(size_t)(b0 + b) * 64 + ld];
        float z = m + e * __expf(0.5f * lv);
        __hip_atomic_store(zbuf + (size_t)(b0 + b) * 64 + ld,
                           __builtin_bit_cast(uint32_t, z),
                           __ATOMIC_RELAXED, __HIP_MEMORY_SCOPE_AGENT);
        drain_vm();
        if (lane == 0)
            __hip_atomic_store(&flags[s * 32], 513u,
                               __ATOMIC_RELAXED, __HIP_MEMORY_SCOPE_AGENT);
    }
    if (wv == 0 && lane < 16)
        while (__hip_atomic_load(&flags[lane * 32], __ATOMIC_RELAXED,
                                 __HIP_MEMORY_SCOPE_AGENT) < 513u) {}
    __syncthreads();

    // h_dec0 = z @ W_init^T + b_init, computed locally into Al
    #pragma unroll
    for (int j = 0; j < 2; ++j) {
        int idx = tid + j * 512;
        int b = idx >> 6, l = idx & 63;
        uint32_t v = __hip_atomic_load(zbuf + (size_t)(b0 + b) * 64 + l,
                                       __ATOMIC_RELAXED, __HIP_MEMORY_SCOPE_AGENT);
        zl[b * 64 + l] = __builtin_bit_cast(float, v);
    }
    __syncthreads();
    {
        int b = tid >> 5, c = tid & 31;
        #pragma unroll
        for (int j = 0; j < 16; ++j) {
            int hd = c * 16 + j;
            float a = binit[hd];
            const float* wr = Winit + (size_t)hd * 64;
            #pragma unroll
            for (int l = 0; l < 64; ++l) a += zl[b * 64 + l] * wr[l];
            Al[b * 520 + hd] = (short)f2b(a);
        }
    }
    #pragma unroll
    for (int r = 0; r < 4; ++r) cst[r] = 0.f;
    __syncthreads();

    // -------- decoder: 100 steps; step d publishes h_{d+1} as R=514+d -----
    short8 wof[16];
    float xbias = 0.f;
    if (s < 4 && wv == 7) {                  // x_hat tile s on wave 7 (no duties)
        xbias = bout[s * 16 + col];
        #pragma unroll
        for (int kt = 0; kt < 16; ++kt)
            wof[kt] = cvt8(Wout + (size_t)(s * 16 + col) * 512 + kt * 32 + q * 8);
    }
    auto xhat_emit = [&](int d) {            // x_hat_d from Al (= h_{d+1})
        f32x4 a2 = {xbias, xbias, xbias, xbias};
        #pragma unroll
        for (int kt = 0; kt < 16; ++kt) {
            short8 a = *(const short8*)(Al + col * 520 + kt * 32 + q * 8);
            a2 = __builtin_amdgcn_mfma_f32_16x16x32_bf16(a, wof[kt], a2, 0, 0, 0);
        }
        #pragma unroll
        for (int r = 0; r < 4; ++r) {
            int b = q * 4 + r;
            out[((size_t)(b0 + b) * 100 + d) * 64 + s * 16 + col] = a2[r];
        }
    };

    load_wfrag_f32(Whh_d);                   // step 0: x0 == 0
    float bias = bih_d[grow] + bhh_d[grow];
    for (uint32_t d = 0; d < 100; ++d) {
        if (d > 0) wait_and_stage(513 + d);  // Al = h_d
        f32x4 acc = {bias, bias, bias, bias};
        #pragma unroll
        for (int kt = 0; kt < 16; ++kt) {
            short8 a = *(const short8*)(Al + col * 520 + kt * 32 + q * 8);
            acc = __builtin_amdgcn_mfma_f32_16x16x32_bf16(a, wfrag[kt], acc, 0, 0, 0);
        }
        cell_update(acc);
        __syncthreads();
        publish_h(514 + d);
        if (d >= 1 && s < 4 && wv == 7) xhat_emit(d - 1);   // off critical path
        if (d == 0) {
            load_wfrag_bf16((const unsigned short*)(ws + WS_WCOMB));
            bias = ((const float*)(ws + WS_BCOMB))[grow];
        }
    }
    wait_and_stage(613);                     // Al = h_100
    if (s < 4 && wv == 7) xhat_emit(99);
}

extern "C" void kernel_launch(void* const* d_in, const int* in_sizes, int n_in,
                              void* d_out, int out_size, void* d_ws, size_t ws_size,
                              hipStream_t stream) {
    (void)in_sizes; (void)n_in; (void)out_size;
    const float* seq   = (const float*)d_in[0];
    const float* eps   = (const float*)d_in[2];
    const float* Wih_e = (const float*)d_in[3];
    const float* Whh_e = (const float*)d_in[4];
    const float* bih_e = (const float*)d_in[5];
    const float* bhh_e = (const float*)d_in[6];
    const float* Wmean = (const float*)d_in[7];
    const float* bmean = (const float*)d_in[8];
    const float* Wlv   = (const float*)d_in[9];
    const float* blv   = (const float*)d_in[10];
    const float* Winit = (const float*)d_in[11];
    const float* binit = (const float*)d_in[12];
    const float* Wih_d = (const float*)d_in[13];
    const float* Whh_d = (const float*)d_in[14];
    const float* bih_d = (const float*)d_in[15];
    const float* bhh_d = (const float*)d_in[16];
    const float* Wout  = (const float*)d_in[17];
    const float* bout  = (const float*)d_in[18];
    unsigned char* ws = (unsigned char*)d_ws;
    float* out = (float*)d_out;

    const bool have_seqb = ws_size >= (size_t)WS_END;
    unsigned short* seqb = have_seqb ? (unsigned short*)(ws + WS_SEQB) : nullptr;

    hipMemsetAsync(ws, 0, WS_ZERO, stream);   // flags + hbuf0 (h0 = 0)
    if (have_seqb)
        seqcvt_kernel<<<4096, 256, 0, stream>>>(seq, seqb);
    wcomb_kernel<<<256, 256, 0, stream>>>(Wih_d, Whh_d, Wout, bih_d, bhh_d, bout, ws);
    vae_persistent<<<128, 512, 0, stream>>>(
        seq, seqb, eps, Wih_e, Whh_e, bih_e, bhh_e,
        Wmean, bmean, Wlv, blv, Winit, binit,
        Whh_d, bih_d, bhh_d, Wout, bout, ws, out);
}